// Round 1
// 1403.239 us; speedup vs baseline: 1.0277x; 1.0277x over previous
//
#include <hip/hip_runtime.h>

// Problem constants
#define BB 2
#define TT 4096
#define CC 64
#define HH 2
#define KK 32
#define VV 32000
#define TC 64                 // chunk length for the scan
#define NC (TT / TC)          // 64 chunks
#define NROWS (BB * TT)       // 8192

typedef __attribute__((ext_vector_type(8))) short short8;   // 8 bf16 = 4 VGPRs
typedef __attribute__((ext_vector_type(4))) float f32x4;    // MFMA C/D

// ---------------------------------------------------------------------------
// x = embed[tokens]
__global__ __launch_bounds__(256) void k_embed(const int* __restrict__ tokens,
                                               const float* __restrict__ embed,
                                               float* __restrict__ X) {
  int id = blockIdx.x * 256 + threadIdx.x;  // float4 index, NROWS*16 total
  int row = id >> 4, c4 = id & 15;
  int tok = tokens[row];
  ((float4*)X)[id] = ((const float4*)embed)[tok * 16 + c4];
}

// ---------------------------------------------------------------------------
// r,k,v = x@W*, d = exp(x@Ww).  Wave m (0..3) handles matrix m; W column in
// registers, x row broadcast via __shfl. No LDS, no syncthreads.
__global__ __launch_bounds__(256) void k_proj(
    const float* __restrict__ X,
    const float* __restrict__ Wr, const float* __restrict__ Wk,
    const float* __restrict__ Wv, const float* __restrict__ Ww,
    float* __restrict__ Rb, float* __restrict__ Kb,
    float* __restrict__ Vb, float* __restrict__ Db) {
  int tid = threadIdx.x;
  int row0 = blockIdx.x * 16;
  int m = tid >> 6, j = tid & 63;
  const float* Wm = (m == 0) ? Wr : (m == 1) ? Wk : (m == 2) ? Wv : Ww;
  float* outp = (m == 0) ? Rb : (m == 1) ? Kb : (m == 2) ? Vb : Db;
  float wreg[64];
#pragma unroll
  for (int c = 0; c < 64; ++c) wreg[c] = Wm[c * 64 + j];  // coalesced per wave
  for (int r = 0; r < 16; ++r) {
    float xv = X[(row0 + r) * 64 + j];  // lane j holds x[row][j]
    float acc = 0.f;
#pragma unroll
    for (int c = 0; c < 64; ++c) acc = fmaf(__shfl(xv, c), wreg[c], acc);
    outp[(row0 + r) * 64 + j] = (m == 3) ? __expf(acc) : acc;
  }
}

// ---------------------------------------------------------------------------
// Phase 1: per (b,h,chunk): Ac[k] = exp(-sum_t d) ; Bc[k][v] = sum_i
// exp(-sum_{j>i} d_j[k]) * k_i[k] * v_i[v]
__global__ __launch_bounds__(1024) void k_phase1(
    const float* __restrict__ Kb, const float* __restrict__ Vb,
    const float* __restrict__ Db, float* __restrict__ Ac,
    float* __restrict__ Bc) {
  __shared__ float kd[TC][KK];  // decay_tail * k
  __shared__ float vt[TC][KK];
  __shared__ float dd[TC][KK];
  __shared__ float kk[TC][KK];
  int chunk = blockIdx.x, bh = blockIdx.y;
  int b = bh >> 1, h = bh & 1;
  int row0 = b * TT + chunk * TC;
  int cb = h * KK;
  int tid = threadIdx.x;
  for (int i = tid; i < TC * KK; i += 1024) {
    int t = i >> 5, k = i & 31;
    int g = (row0 + t) * CC + cb + k;
    dd[t][k] = Db[g];
    kk[t][k] = Kb[g];
    vt[t][k] = Vb[g];
  }
  __syncthreads();
  if (tid < KK) {  // suffix accumulation of d per k-column
    int k = tid;
    float s = 0.f;
    for (int i = TC - 1; i >= 0; --i) {
      kd[i][k] = __expf(-s) * kk[i][k];  // s = sum_{j>i} d_j
      s += dd[i][k];
    }
    Ac[(bh * NC + chunk) * KK + k] = __expf(-s);
  }
  __syncthreads();
  int k = tid >> 5, v = tid & 31;
  float acc = 0.f;
#pragma unroll 8
  for (int i = 0; i < TC; ++i) acc = fmaf(kd[i][k], vt[i][v], acc);
  Bc[((bh * NC + chunk) * KK + k) * KK + v] = acc;
}

// ---------------------------------------------------------------------------
// Phase 2: serial over chunks per (b,h): S0[c]=S; S = Ac[c]*S + Bc[c]
__global__ __launch_bounds__(1024) void k_phase2(
    const float* __restrict__ Ac, const float* __restrict__ Bc,
    float* __restrict__ S0) {
  int bh = blockIdx.x;
  int tid = threadIdx.x;
  int k = tid >> 5, v = tid & 31;
  const float* Ab = Ac + bh * NC * KK;
  const float* Bb = Bc + bh * NC * KK * KK;
  float* Sb = S0 + bh * NC * KK * KK;
  float S = 0.f;
#pragma unroll 1
  for (int cc = 0; cc < NC; cc += 8) {  // prefetch groups of 8
    float av[8], bv[8];
#pragma unroll
    for (int q = 0; q < 8; ++q) av[q] = Ab[(cc + q) * KK + k];
#pragma unroll
    for (int q = 0; q < 8; ++q) bv[q] = Bb[((cc + q) * KK + k) * KK + v];
#pragma unroll
    for (int q = 0; q < 8; ++q) {
      Sb[((cc + q) * KK + k) * KK + v] = S;
      S = fmaf(av[q], S, bv[q]);
    }
  }
}

// ---------------------------------------------------------------------------
// Phase 3: intra-chunk attention + carry-in.
// P[t][k] = sum_{j<t} d_j[k] (exclusive prefix).
// Sc[t][i] = sum_k r_t k_i exp(P[i+1]-P[t])  (i<t);  Sc[t][t] = sum_k r u k.
// o[t][v] = sum_{i<=t} Sc[t][i] v_i[v] + sum_k r_t[k] exp(-P[t][k]) S0[k][v]
__global__ __launch_bounds__(512) void k_phase3(
    const float* __restrict__ Rb, const float* __restrict__ Kb,
    const float* __restrict__ Vb, const float* __restrict__ Db,
    const float* __restrict__ S0, const float* __restrict__ u,
    float* __restrict__ O) {
  __shared__ float rs[TC][KK + 1];
  __shared__ float ks[TC][KK + 1];
  __shared__ float vs[TC][KK + 1];
  __shared__ float Ps[TC][KK + 1];
  __shared__ float Sc[TC][TC + 1];
  __shared__ float S0s[KK][KK + 1];
  __shared__ float us[KK];
  int chunk = blockIdx.x, bh = blockIdx.y;
  int b = bh >> 1, h = bh & 1;
  int row0 = b * TT + chunk * TC;
  int cb = h * KK;
  int tid = threadIdx.x;
  for (int i = tid; i < TC * KK; i += 512) {
    int t = i >> 5, k = i & 31;
    int g = (row0 + t) * CC + cb + k;
    rs[t][k] = Rb[g];
    ks[t][k] = Kb[g];
    vs[t][k] = Vb[g];
    Ps[t][k] = Db[g];  // holds d for now
  }
  for (int i = tid; i < KK * KK; i += 512) {
    int k = i >> 5, v = i & 31;
    S0s[k][v] = S0[((bh * NC + chunk) * KK + k) * KK + v];
  }
  if (tid < KK) us[tid] = u[h * KK + tid];
  __syncthreads();
  if (tid < KK) {  // in-place exclusive prefix over t
    float run = 0.f;
    for (int t = 0; t < TC; ++t) {
      float dv = Ps[t][tid];
      Ps[t][tid] = run;
      run += dv;
    }
  }
  __syncthreads();
  for (int e = tid; e < TC * TC; e += 512) {
    int t = e >> 6, i = e & 63;
    float val = 0.f;
    if (i < t) {
#pragma unroll 8
      for (int k = 0; k < KK; ++k)
        val += rs[t][k] * ks[i][k] * __expf(Ps[i + 1][k] - Ps[t][k]);
    } else if (i == t) {
#pragma unroll 8
      for (int k = 0; k < KK; ++k) val += rs[t][k] * us[k] * ks[t][k];
    }
    Sc[t][i] = val;  // zero-padded above diagonal
  }
  __syncthreads();
  for (int i = tid; i < TC * KK; i += 512) {  // r *= exp(-P) for carry-in term
    int t = i >> 5, k = i & 31;
    rs[t][k] *= __expf(-Ps[t][k]);
  }
  __syncthreads();
  for (int e = tid; e < TC * KK; e += 512) {
    int t = e >> 5, v = e & 31;
    float acc = 0.f;
    for (int i = 0; i <= t; ++i) acc = fmaf(Sc[t][i], vs[i][v], acc);
#pragma unroll 8
    for (int k = 0; k < KK; ++k) acc = fmaf(rs[t][k], S0s[k][v], acc);
    O[(row0 + t) * CC + cb + v] = acc;
  }
}

// ---------------------------------------------------------------------------
// X += O @ Wo  (residual). Same no-LDS shfl trick as k_proj.
__global__ __launch_bounds__(256) void k_outproj(
    const float* __restrict__ O, const float* __restrict__ Wo,
    float* __restrict__ X) {
  int tid = threadIdx.x;
  int row0 = blockIdx.x * 16;
  int wv = tid >> 6, j = tid & 63;
  float wreg[64];
#pragma unroll
  for (int c = 0; c < 64; ++c) wreg[c] = Wo[c * 64 + j];
  for (int rr = 0; rr < 4; ++rr) {
    int row = row0 + wv * 4 + rr;
    float ov = O[row * 64 + j];
    float acc = 0.f;
#pragma unroll
    for (int c = 0; c < 64; ++c) acc = fmaf(__shfl(ov, c), wreg[c], acc);
    X[row * 64 + j] += acc;
  }
}

// ---------------------------------------------------------------------------
// Split fp32 -> bf16 hi (truncated, exact) + bf16 lo (RNE of remainder).
// x ~= hi + lo with relative error ~2^-17.
__global__ __launch_bounds__(256) void k_split(const float* __restrict__ src,
                                               unsigned short* __restrict__ hi,
                                               unsigned short* __restrict__ lo,
                                               int n4) {
  int id = blockIdx.x * 256 + threadIdx.x;
  if (id >= n4) return;
  float4 x = ((const float4*)src)[id];
  float xs[4] = {x.x, x.y, x.z, x.w};
  unsigned short h[4], l[4];
#pragma unroll
  for (int i = 0; i < 4; ++i) {
    unsigned int b = __float_as_uint(xs[i]);
    unsigned int hb = b & 0xFFFF0000u;           // truncate -> exact hi
    h[i] = (unsigned short)(hb >> 16);
    float lof = xs[i] - __uint_as_float(hb);     // exact remainder
    unsigned int lb = __float_as_uint(lof);
    lb += 0x7FFFu + ((lb >> 16) & 1u);           // RNE to bf16
    l[i] = (unsigned short)(lb >> 16);
  }
  ((ushort4*)hi)[id] = make_ushort4(h[0], h[1], h[2], h[3]);
  ((ushort4*)lo)[id] = make_ushort4(l[0], l[1], l[2], l[3]);
}

// ---------------------------------------------------------------------------
// logits = X @ embed^T via bf16x3 MFMA: Xhi*Ehi + Xhi*Elo + Xlo*Ehi.
// Both operands are k-contiguous rows of 64 bf16 -> direct 16B/lane fragment
// loads from global, no LDS. C/D layout: col=lane&15, row=(lane>>4)*4+reg
// (HW-verified). 4 waves/block; block tile 64 rows x 128 cols; wave tile
// 32 rows x 64 cols (2x4 C-frags).
__global__ __launch_bounds__(256) void k_head_mfma(
    const unsigned short* __restrict__ Xhi, const unsigned short* __restrict__ Xlo,
    const unsigned short* __restrict__ Ehi, const unsigned short* __restrict__ Elo,
    float* __restrict__ out) {
  int tid = threadIdx.x;
  int wave = tid >> 6, lane = tid & 63;
  int lg = lane >> 4, lr = lane & 15;
  int row0 = blockIdx.y * 64 + (wave & 1) * 32;   // 2 row-tiles of 16
  int col0 = blockIdx.x * 128 + (wave >> 1) * 64; // 4 col-tiles of 16

  f32x4 acc[2][4];
#pragma unroll
  for (int rt = 0; rt < 2; ++rt)
#pragma unroll
    for (int ct = 0; ct < 4; ++ct) acc[rt][ct] = (f32x4){0.f, 0.f, 0.f, 0.f};

  const unsigned short* Asrc[3] = {Xhi, Xhi, Xlo};
  const unsigned short* Bsrc[3] = {Ehi, Elo, Ehi};

#pragma unroll
  for (int term = 0; term < 3; ++term) {
    const unsigned short* A = Asrc[term];
    const unsigned short* B = Bsrc[term];
    short8 a[2][2], bfr[2][4];
#pragma unroll
    for (int rt = 0; rt < 2; ++rt)
#pragma unroll
      for (int kk2 = 0; kk2 < 2; ++kk2)
        a[rt][kk2] = *(const short8*)(A + (size_t)(row0 + rt * 16 + lr) * CC +
                                      kk2 * 32 + lg * 8);
#pragma unroll
    for (int ct = 0; ct < 4; ++ct)
#pragma unroll
      for (int kk2 = 0; kk2 < 2; ++kk2)
        bfr[kk2][ct] = *(const short8*)(B + (size_t)(col0 + ct * 16 + lr) * CC +
                                        kk2 * 32 + lg * 8);
#pragma unroll
    for (int rt = 0; rt < 2; ++rt)
#pragma unroll
      for (int ct = 0; ct < 4; ++ct)
#pragma unroll
        for (int kk2 = 0; kk2 < 2; ++kk2)
          acc[rt][ct] = __builtin_amdgcn_mfma_f32_16x16x32_bf16(
              a[rt][kk2], bfr[kk2][ct], acc[rt][ct], 0, 0, 0);
  }

#pragma unroll
  for (int rt = 0; rt < 2; ++rt)
#pragma unroll
    for (int ct = 0; ct < 4; ++ct) {
      int col = col0 + ct * 16 + lr;
      int rbase = row0 + rt * 16 + lg * 4;
#pragma unroll
      for (int rg = 0; rg < 4; ++rg)
        out[(size_t)(rbase + rg) * VV + col] = acc[rt][ct][rg];
    }
}

// ---------------------------------------------------------------------------
extern "C" void kernel_launch(void* const* d_in, const int* in_sizes, int n_in,
                              void* d_out, int out_size, void* d_ws,
                              size_t ws_size, hipStream_t stream) {
  const int* tokens = (const int*)d_in[0];
  const float* embed = (const float*)d_in[1];
  const float* Wr = (const float*)d_in[2];
  const float* Wk = (const float*)d_in[3];
  const float* Wv = (const float*)d_in[4];
  const float* Ww = (const float*)d_in[5];
  const float* Wo = (const float*)d_in[6];
  const float* u = (const float*)d_in[7];
  float* out = (float*)d_out;

  float* X = (float*)d_ws;                    // [NROWS][CC]
  float* Rb = X + NROWS * CC;
  float* Kb = Rb + NROWS * CC;
  float* Vb = Kb + NROWS * CC;
  float* Db = Vb + NROWS * CC;                // d = exp(x@Ww)
  float* O = Db + NROWS * CC;
  float* Ac = O + NROWS * CC;                 // [B*H][NC][K]
  float* Bc = Ac + BB * HH * NC * KK;         // [B*H][NC][K][K]
  float* S0 = Bc + BB * HH * NC * KK * KK;    // [B*H][NC][K][K]
  unsigned short* Ehi = (unsigned short*)(S0 + BB * HH * NC * KK * KK);
  unsigned short* Elo = Ehi + (size_t)VV * CC;
  unsigned short* Xhi = Elo + (size_t)VV * CC;
  unsigned short* Xlo = Xhi + (size_t)NROWS * CC;

  k_embed<<<NROWS * 16 / 256, 256, 0, stream>>>(tokens, embed, X);
  // embed split is independent of the layer pipeline; do it up front
  k_split<<<(VV * CC / 4 + 255) / 256, 256, 0, stream>>>(embed, Ehi, Elo,
                                                         VV * CC / 4);
  for (int l = 0; l < 2; ++l) {
    const float* Wrl = Wr + l * CC * CC;
    const float* Wkl = Wk + l * CC * CC;
    const float* Wvl = Wv + l * CC * CC;
    const float* Wwl = Ww + l * CC * CC;
    const float* Wol = Wo + l * CC * CC;
    const float* ul = u + l * HH * KK;
    k_proj<<<NROWS / 16, 256, 0, stream>>>(X, Wrl, Wkl, Wvl, Wwl, Rb, Kb, Vb,
                                           Db);
    k_phase1<<<dim3(NC, BB * HH), 1024, 0, stream>>>(Kb, Vb, Db, Ac, Bc);
    k_phase2<<<BB * HH, 1024, 0, stream>>>(Ac, Bc, S0);
    k_phase3<<<dim3(NC, BB * HH), 512, 0, stream>>>(Rb, Kb, Vb, Db, S0, ul, O);
    k_outproj<<<NROWS / 16, 256, 0, stream>>>(O, Wol, X);
  }
  k_split<<<(NROWS * CC / 4 + 255) / 256, 256, 0, stream>>>(X, Xhi, Xlo,
                                                            NROWS * CC / 4);
  k_head_mfma<<<dim3(VV / 128, NROWS / 64), 256, 0, stream>>>(Xhi, Xlo, Ehi,
                                                              Elo, out);
}